// Round 14
// baseline (501.581 us; speedup 1.0000x reference)
//
#include <hip/hip_runtime.h>
#include <cstddef>

// FNO spectral conv via single-product bf16 MFMA (manual RNE):
//   gen : twiddle tables in MFMA fragment order (384 KB, L2-hot)
//   FA  : x -> T_t bf16   (DFT along w)   4096 blocks, occ 4, MLP-16 loads
//   FB  : T_t -> Y float2 (DFT along h)   1024 blocks, occ 4
//   mix : per-mode complex channel GEMM, 4 modes/block (32 KB LDS -> 4 blk/CU,
//         2x waves vs r13's 8-mode/64KB/2-blk: was latency-bound on W stream),
//         XCD co-location bid = kyq*64+kx
//   INV : fused IB+IA per (bo, h-quarter), 3 barriers, 4 blocks/CU
// Ledger: r10 nt BAD; r11 occ5+unroll4 BAD; r12 fa-MLP good; r13 fused-inv
// good (-53us). absmax must stay 7.629395e-06 (bit-identical arithmetic).

typedef __attribute__((ext_vector_type(8))) short bf16x8;
typedef __attribute__((ext_vector_type(4))) float f32x4;
typedef unsigned short u16;

static constexpr float T256 = 6.28318530717958647692f / 256.0f;
// f-slot bases (each slot = 64 lanes x 8 u16 = 16 B/lane)
static constexpr int FB_OFF = 4096, IB_OFF = 12288, IA_OFF = 20480;

// 3-op RNE bf16 (no NaN path — inputs finite by construction)
__device__ __forceinline__ u16 f2bf(float f) {
    unsigned u = __float_as_uint(f);
    return (u16)((u + 0x7FFFu + ((u >> 16) & 1u)) >> 16);
}
__device__ __forceinline__ ushort4 cvt4(const f32x4& a) {
    ushort4 o;
    o.x = f2bf(a[0]); o.y = f2bf(a[1]); o.z = f2bf(a[2]); o.w = f2bf(a[3]);
    return o;
}

// ---------------------------------------------------------------------------
// twiddle gen (proven layout)
// ---------------------------------------------------------------------------
__global__ __launch_bounds__(256) void gen_kernel(u16* __restrict__ tw) {
    const int t = blockIdx.x * 256 + threadIdx.x;       // 0..24575
    const int lane = t & 63, f = t >> 6;
    const int lr = lane & 15, lg = lane >> 4;
    bf16x8 hi;
#pragma unroll
    for (int j = 0; j < 8; ++j) {
        float v = 0.0f;
        if (f < 64) {                                   // FA  B[w][col]
            int nf = f >> 3, ks = f & 7;
            int col = nf * 16 + lr, k = ks * 32 + lg * 8 + j;
            int cc = (col < 64) ? col : (col - 64);
            float ss, sc; sincosf(T256 * (float)((k * cc) & 255), &ss, &sc);
            v = (col < 64) ? sc : ss;
        } else if (f < 192) {                           // FB  B[k][col]
            int fid = f - 64, nf = fid >> 4, ks = fid & 15;
            int col = nf * 16 + lr, k = ks * 32 + lg * 8 + j;
            int kx = col & 63, im = col >> 6;
            int h = k & 255, part = k >> 8;
            float ss, sc; sincosf(T256 * (float)((h * kx) & 255), &ss, &sc);
            if (im == 0) v = part ? -ss : sc;
            else         v = part ? -sc : -ss;
        } else if (f < 320) {                           // IB  B[k][col]
            int fid = f - 192, nf = fid >> 2, ks = fid & 3;
            int col = nf * 16 + lr, k = ks * 32 + lg * 8 + j;
            int h = col & 255, reim = col >> 8;
            int kx = k & 63, part = k >> 6;
            float ss, sc; sincosf(T256 * (float)((h * kx) & 255), &ss, &sc);
            if (reim == 0) v = part ? -ss : sc;
            else           v = part ?  sc :  ss;
        } else {                                        // IA  A[w][k]
            int fid = f - 320, mf = fid >> 2, ks = fid & 3;
            int w = mf * 16 + lr, k = ks * 32 + lg * 8 + j;
            int ky = k & 63, part = k >> 6;
            float wt = (ky ? 2.0f : 1.0f) * (1.0f / 65536.0f);
            float ss, sc; sincosf(T256 * (float)((w * ky) & 255), &ss, &sc);
            v = part ? (-wt * ss) : (wt * sc);
        }
        hi[j] = (short)f2bf(v);
    }
    *(bf16x8*)(tw + (size_t)t * 8) = hi;
}

// ---------------------------------------------------------------------------
// FA: block = (bi, h-chunk of 64). [64 h x 128 col(cs,ky)], K=256(w).
// All 16 x-loads issued up front (MLP); VGPR ~119 < occ-4 cap 128. (r12 exact)
// ---------------------------------------------------------------------------
__global__ __launch_bounds__(256, 4) void fa_kernel(const float* __restrict__ x,
                                                    const u16* __restrict__ tw,
                                                    u16* __restrict__ Tt) {
    const int bi = blockIdx.x >> 2, hc = blockIdx.x & 3;
    const int tid = threadIdx.x;
    const int lane = tid & 63, wid = tid >> 6;
    const int lr = lane & 15, lg = lane >> 4;

    __shared__ u16 Ls[128][72];     // 18432 B

    f32x4 acc[8] = {};
    const float* xr = x + (size_t)bi * 65536 + (size_t)(hc * 64 + wid * 16 + lr) * 256 + lg * 8;

    f32x4 xv[16];
#pragma unroll
    for (int ks = 0; ks < 8; ++ks) {
        xv[2 * ks]     = *(const f32x4*)(xr + ks * 32);
        xv[2 * ks + 1] = *(const f32x4*)(xr + ks * 32 + 4);
    }

#pragma unroll
    for (int ks = 0; ks < 8; ++ks) {
        bf16x8 ah;
#pragma unroll
        for (int j = 0; j < 4; ++j) {
            ah[j]     = (short)f2bf(xv[2 * ks][j]);
            ah[4 + j] = (short)f2bf(xv[2 * ks + 1][j]);
        }
#pragma unroll
        for (int nf = 0; nf < 8; ++nf) {
            bf16x8 bh = *(const bf16x8*)(tw + ((size_t)(nf * 8 + ks) * 64 + lane) * 8);
            acc[nf] = __builtin_amdgcn_mfma_f32_16x16x32_bf16(ah, bh, acc[nf], 0, 0, 0);
        }
    }

#pragma unroll
    for (int nf = 0; nf < 8; ++nf)
        *(ushort4*)&Ls[nf * 16 + lr][wid * 16 + lg * 4] = cvt4(acc[nf]);
    __syncthreads();

    {
        const int col = tid >> 1, half = tid & 1;
        const int ky = col & 63, cs = col >> 6;
        u16* dst = Tt + (size_t)bi * 32768 + (size_t)ky * 512 + cs * 256 + hc * 64 + half * 32;
        const u16* srcp = &Ls[col][half * 32];
#pragma unroll
        for (int q = 0; q < 4; ++q)
            *(bf16x8*)(dst + q * 8) = *(const bf16x8*)(srcp + q * 8);
    }
}

// ---------------------------------------------------------------------------
// FB: block = bi. [64 ky x 128 col(im,kx)], K=512(cs,h).  (r9/r12 exact)
// ---------------------------------------------------------------------------
__global__ __launch_bounds__(256, 4) void fb_kernel(const u16* __restrict__ Tt,
                                                    const u16* __restrict__ tw,
                                                    float2* __restrict__ Y) {
    const int bi = blockIdx.x;
    const int tid = threadIdx.x;
    const int lane = tid & 63, wid = tid >> 6;
    const int lr = lane & 15, lg = lane >> 4;

    f32x4 acc[8] = {};
    const u16* ar = Tt + (size_t)bi * 32768 + (size_t)(wid * 16 + lr) * 512 + lg * 8;

#pragma unroll 2
    for (int ks = 0; ks < 16; ++ks) {
        bf16x8 ah = *(const bf16x8*)(ar + ks * 32);
#pragma unroll
        for (int nf = 0; nf < 8; ++nf) {
            bf16x8 bh = *(const bf16x8*)(tw + ((size_t)FB_OFF + (size_t)(nf * 16 + ks) * 64 + lane) * 8);
            acc[nf] = __builtin_amdgcn_mfma_f32_16x16x32_bf16(ah, bh, acc[nf], 0, 0, 0);
        }
    }

    __shared__ float L[64][129];
#pragma unroll
    for (int nf = 0; nf < 8; ++nf) {
        int col = nf * 16 + lr;
        int row = wid * 16 + lg * 4;
#pragma unroll
        for (int r = 0; r < 4; ++r) L[row + r][col] = acc[nf][r];
    }
    __syncthreads();
#pragma unroll
    for (int s = 0; s < 16; ++s) {
        int n = tid + s * 256;          // n = kx*64 + ky
        int ky = n & 63, kx = n >> 6;
        Y[(size_t)bi * 4096 + n] = make_float2(L[ky][kx], L[ky][64 + kx]);
    }
}

// ---------------------------------------------------------------------------
// MIX: in-place Y -> M, 4 modes/block. Grid = 1024: kx = bid&63, kyq = bid>>6.
// bid%8 = kx%8 for all 16 kyq-siblings of a kx -> same XCD (W lines shared).
// LDS 32 KB -> 4 blocks/CU (2x r13 occupancy; W-latency hiding).
// Per-output fma chain identical to r13 -> bit-identical M.
// ---------------------------------------------------------------------------
__global__ __launch_bounds__(256, 4) void mix_kernel(const float2* Yin,
                                                     const float* __restrict__ Wg,
                                                     float2* Mx) {
    const int kx    = blockIdx.x & 63;
    const int kyq   = blockIdx.x >> 6;      // 0..15
    const int tid   = threadIdx.x;
    const int kxky0 = kx * 64 + kyq * 4;

    __shared__ float2 Ys[128 * 32];         // [i][b][j4] = 32 KB

#pragma unroll
    for (int s = 0; s < 16; ++s) {
        int n = tid + s * 256;              // 0..4095
        int b = n >> 9, i = (n >> 2) & 127, j = n & 3;
        Ys[i * 32 + b * 4 + j] = Yin[(size_t)(b * 128 + i) * 4096 + kxky0 + j];
    }
    __syncthreads();

    const int o  = tid & 127;
    const int bh = tid >> 7;                // 0: b0-3, 1: b4-7

    float accre[4][4] = {{0.f}}, accim[4][4] = {{0.f}};
    const float* wp = Wg + ((size_t)o * 4096 + kxky0) * 2;
    const size_t istride = (size_t)128 * 4096 * 2;

#pragma unroll 2
    for (int i = 0; i < 128; ++i) {
        float4 wa = *(const float4*)(wp + (size_t)i * istride);
        float4 wb = *(const float4*)(wp + (size_t)i * istride + 4);
#pragma unroll
        for (int b = 0; b < 4; ++b) {
            float4 y01 = *(const float4*)&Ys[i * 32 + (bh * 4 + b) * 4];
            float4 y23 = *(const float4*)&Ys[i * 32 + (bh * 4 + b) * 4 + 2];
            accre[b][0] = fmaf(y01.x, wa.x, fmaf(-y01.y, wa.y, accre[b][0]));
            accim[b][0] = fmaf(y01.x, wa.y, fmaf( y01.y, wa.x, accim[b][0]));
            accre[b][1] = fmaf(y01.z, wa.z, fmaf(-y01.w, wa.w, accre[b][1]));
            accim[b][1] = fmaf(y01.z, wa.w, fmaf( y01.w, wa.z, accim[b][1]));
            accre[b][2] = fmaf(y23.x, wb.x, fmaf(-y23.y, wb.y, accre[b][2]));
            accim[b][2] = fmaf(y23.x, wb.y, fmaf( y23.y, wb.x, accim[b][2]));
            accre[b][3] = fmaf(y23.z, wb.z, fmaf(-y23.w, wb.w, accre[b][3]));
            accim[b][3] = fmaf(y23.z, wb.w, fmaf( y23.w, wb.z, accim[b][3]));
        }
    }
#pragma unroll
    for (int b = 0; b < 4; ++b) {
        float2* mo = Mx + (size_t)((bh * 4 + b) * 128 + o) * 4096 + kxky0;
        *(float4*)(mo)     = make_float4(accre[b][0], accim[b][0], accre[b][1], accim[b][1]);
        *(float4*)(mo + 2) = make_float4(accre[b][2], accim[b][2], accre[b][3], accim[b][3]);
    }
}

// ---------------------------------------------------------------------------
// INV (fused IB+IA): block = (bo, h-quarter hq). (r13 exact)
//   stage M -> LDS Ah[ky][k] (RNE bf16)                       [1 barrier]
//   IB: [64 ky x 128 (reim, hloc)] K=128 -> D-frags -> LDS Gh [1 barrier]
//   IA: [256 w x 64 hloc] K=128, A=twIA, B=Gh -> out          [1 barrier]
// ---------------------------------------------------------------------------
__global__ __launch_bounds__(256, 4) void inv_kernel(const float2* __restrict__ M,
                                                     const u16* __restrict__ tw,
                                                     float* __restrict__ out) {
    const int bo = blockIdx.x >> 2, hq = blockIdx.x & 3;
    const int tid = threadIdx.x;
    const int lane = tid & 63, wid = tid >> 6;
    const int lr = lane & 15, lg = lane >> 4;

    __shared__ u16 Ah[64][136];     // 17408 B
    __shared__ u16 Gh[64][136];     // 17408 B

    const float2* Mb = M + (size_t)bo * 4096;
#pragma unroll
    for (int s = 0; s < 16; ++s) {
        int n = tid + s * 256;
        float2 v = Mb[n];
        int kx = n >> 6, ky = n & 63;
        Ah[ky][kx]      = f2bf(v.x);
        Ah[ky][64 + kx] = f2bf(v.y);
    }
    __syncthreads();

    // ---- IB ----
    {
        const int reim = wid >> 1, csub = wid & 1;
        f32x4 bacc[4][2] = {};
#pragma unroll
        for (int ks = 0; ks < 4; ++ks) {
            bf16x8 bh[2];
#pragma unroll
            for (int nf = 0; nf < 2; ++nf) {
                int nf_g = reim * 16 + hq * 4 + csub * 2 + nf;
                bh[nf] = *(const bf16x8*)(tw + ((size_t)IB_OFF + (size_t)(nf_g * 4 + ks) * 64 + lane) * 8);
            }
#pragma unroll
            for (int mf = 0; mf < 4; ++mf) {
                bf16x8 ah = *(const bf16x8*)&Ah[mf * 16 + lr][ks * 32 + lg * 8];
#pragma unroll
                for (int nf = 0; nf < 2; ++nf)
                    bacc[mf][nf] = __builtin_amdgcn_mfma_f32_16x16x32_bf16(ah, bh[nf], bacc[mf][nf], 0, 0, 0);
            }
        }
        __syncthreads();
#pragma unroll
        for (int mf = 0; mf < 4; ++mf)
#pragma unroll
            for (int nf = 0; nf < 2; ++nf) {
                int hloc = csub * 32 + nf * 16 + lr;
                int kk   = reim * 64 + mf * 16 + lg * 4;
                *(ushort4*)&Gh[hloc][kk] = cvt4(bacc[mf][nf]);
            }
    }
    __syncthreads();

    // ---- IA ----
    {
        f32x4 cacc[4][4] = {};
#pragma unroll
        for (int ks = 0; ks < 4; ++ks) {
            bf16x8 ah[4];
#pragma unroll
            for (int mf = 0; mf < 4; ++mf) {
                int mf_g = wid * 4 + mf;
                ah[mf] = *(const bf16x8*)(tw + ((size_t)IA_OFF + (size_t)(mf_g * 4 + ks) * 64 + lane) * 8);
            }
#pragma unroll
            for (int nf = 0; nf < 4; ++nf) {
                bf16x8 bh = *(const bf16x8*)&Gh[nf * 16 + lr][ks * 32 + lg * 8];
#pragma unroll
                for (int mf = 0; mf < 4; ++mf)
                    cacc[mf][nf] = __builtin_amdgcn_mfma_f32_16x16x32_bf16(ah[mf], bh, cacc[mf][nf], 0, 0, 0);
            }
        }
#pragma unroll
        for (int mf = 0; mf < 4; ++mf)
#pragma unroll
            for (int nf = 0; nf < 4; ++nf) {
                int w0 = wid * 64 + mf * 16 + lg * 4;
                int h  = hq * 64 + nf * 16 + lr;
                *(f32x4*)(out + (size_t)bo * 65536 + (size_t)h * 256 + w0) = cacc[mf][nf];
            }
    }
}

// ---------------------------------------------------------------------------
extern "C" void kernel_launch(void* const* d_in, const int* in_sizes, int n_in,
                              void* d_out, int out_size, void* d_ws, size_t ws_size,
                              hipStream_t stream) {
    (void)in_sizes; (void)n_in; (void)out_size; (void)ws_size;
    const float* x  = (const float*)d_in[0];
    const float* wg = (const float*)d_in[1];
    float* outp = (float*)d_out;

    u16*    tw = (u16*)d_ws;                                          // 384 KB
    float2* Y  = (float2*)((char*)d_ws + 1048576);                    // 33.5 MB
    u16*    Tt = (u16*)((char*)d_ws + 1048576 + 33554432);            // 67 MB

    gen_kernel<<<96, 256, 0, stream>>>(tw);
    fa_kernel<<<4096, 256, 0, stream>>>(x, tw, Tt);
    fb_kernel<<<1024, 256, 0, stream>>>(Tt, tw, Y);
    mix_kernel<<<1024, 256, 0, stream>>>(Y, wg, Y);
    inv_kernel<<<4096, 256, 0, stream>>>(Y, tw, outp);
}

// Round 15
// 421.611 us; speedup vs baseline: 1.1897x; 1.1897x over previous
//
#include <hip/hip_runtime.h>
#include <cstddef>

// FNO spectral conv via single-product bf16 MFMA (manual RNE):
//   gen : twiddle tables in MFMA fragment order (384 KB, L2-hot)
//   FA  : x -> T_t bf16   (DFT along w)   4096 blocks, occ 4, MLP-16 loads
//   FB  : T_t -> Y float2 (DFT along h)   1024 blocks, occ 4
//   mix : per-mode complex channel GEMM, 8 modes/block, 512 blocks, 64KB LDS,
//         XCD co-location (bid = kyo*64+kx), i-loop unroll 4 (W-MLP)
//   INV : fused IB+IA per (bo, h-quarter), 3 barriers, 4 blocks/CU
// Ledger: r10 nt BAD; r11 occ5+unroll4@cap102 BAD; r12 fa-MLP good; r13
// fused-inv good; r14 4-mode mix BAD (+130us: duplicate W loads, worse line
// dedup). This round = r13 exact + mix unroll 2->4 (VGPR cap 256, use ~119).
// absmax must stay 7.629395e-06 (bit-identical arithmetic).

typedef __attribute__((ext_vector_type(8))) short bf16x8;
typedef __attribute__((ext_vector_type(4))) float f32x4;
typedef unsigned short u16;

static constexpr float T256 = 6.28318530717958647692f / 256.0f;
// f-slot bases (each slot = 64 lanes x 8 u16 = 16 B/lane)
static constexpr int FB_OFF = 4096, IB_OFF = 12288, IA_OFF = 20480;

// 3-op RNE bf16 (no NaN path — inputs finite by construction)
__device__ __forceinline__ u16 f2bf(float f) {
    unsigned u = __float_as_uint(f);
    return (u16)((u + 0x7FFFu + ((u >> 16) & 1u)) >> 16);
}
__device__ __forceinline__ ushort4 cvt4(const f32x4& a) {
    ushort4 o;
    o.x = f2bf(a[0]); o.y = f2bf(a[1]); o.z = f2bf(a[2]); o.w = f2bf(a[3]);
    return o;
}

// ---------------------------------------------------------------------------
// twiddle gen (proven layout)
// ---------------------------------------------------------------------------
__global__ __launch_bounds__(256) void gen_kernel(u16* __restrict__ tw) {
    const int t = blockIdx.x * 256 + threadIdx.x;       // 0..24575
    const int lane = t & 63, f = t >> 6;
    const int lr = lane & 15, lg = lane >> 4;
    bf16x8 hi;
#pragma unroll
    for (int j = 0; j < 8; ++j) {
        float v = 0.0f;
        if (f < 64) {                                   // FA  B[w][col]
            int nf = f >> 3, ks = f & 7;
            int col = nf * 16 + lr, k = ks * 32 + lg * 8 + j;
            int cc = (col < 64) ? col : (col - 64);
            float ss, sc; sincosf(T256 * (float)((k * cc) & 255), &ss, &sc);
            v = (col < 64) ? sc : ss;
        } else if (f < 192) {                           // FB  B[k][col]
            int fid = f - 64, nf = fid >> 4, ks = fid & 15;
            int col = nf * 16 + lr, k = ks * 32 + lg * 8 + j;
            int kx = col & 63, im = col >> 6;
            int h = k & 255, part = k >> 8;
            float ss, sc; sincosf(T256 * (float)((h * kx) & 255), &ss, &sc);
            if (im == 0) v = part ? -ss : sc;
            else         v = part ? -sc : -ss;
        } else if (f < 320) {                           // IB  B[k][col]
            int fid = f - 192, nf = fid >> 2, ks = fid & 3;
            int col = nf * 16 + lr, k = ks * 32 + lg * 8 + j;
            int h = col & 255, reim = col >> 8;
            int kx = k & 63, part = k >> 6;
            float ss, sc; sincosf(T256 * (float)((h * kx) & 255), &ss, &sc);
            if (reim == 0) v = part ? -ss : sc;
            else           v = part ?  sc :  ss;
        } else {                                        // IA  A[w][k]
            int fid = f - 320, mf = fid >> 2, ks = fid & 3;
            int w = mf * 16 + lr, k = ks * 32 + lg * 8 + j;
            int ky = k & 63, part = k >> 6;
            float wt = (ky ? 2.0f : 1.0f) * (1.0f / 65536.0f);
            float ss, sc; sincosf(T256 * (float)((w * ky) & 255), &ss, &sc);
            v = part ? (-wt * ss) : (wt * sc);
        }
        hi[j] = (short)f2bf(v);
    }
    *(bf16x8*)(tw + (size_t)t * 8) = hi;
}

// ---------------------------------------------------------------------------
// FA: block = (bi, h-chunk of 64). [64 h x 128 col(cs,ky)], K=256(w).
// All 16 x-loads issued up front (MLP); VGPR ~119 < occ-4 cap 128. (r12 exact)
// ---------------------------------------------------------------------------
__global__ __launch_bounds__(256, 4) void fa_kernel(const float* __restrict__ x,
                                                    const u16* __restrict__ tw,
                                                    u16* __restrict__ Tt) {
    const int bi = blockIdx.x >> 2, hc = blockIdx.x & 3;
    const int tid = threadIdx.x;
    const int lane = tid & 63, wid = tid >> 6;
    const int lr = lane & 15, lg = lane >> 4;

    __shared__ u16 Ls[128][72];     // 18432 B

    f32x4 acc[8] = {};
    const float* xr = x + (size_t)bi * 65536 + (size_t)(hc * 64 + wid * 16 + lr) * 256 + lg * 8;

    f32x4 xv[16];
#pragma unroll
    for (int ks = 0; ks < 8; ++ks) {
        xv[2 * ks]     = *(const f32x4*)(xr + ks * 32);
        xv[2 * ks + 1] = *(const f32x4*)(xr + ks * 32 + 4);
    }

#pragma unroll
    for (int ks = 0; ks < 8; ++ks) {
        bf16x8 ah;
#pragma unroll
        for (int j = 0; j < 4; ++j) {
            ah[j]     = (short)f2bf(xv[2 * ks][j]);
            ah[4 + j] = (short)f2bf(xv[2 * ks + 1][j]);
        }
#pragma unroll
        for (int nf = 0; nf < 8; ++nf) {
            bf16x8 bh = *(const bf16x8*)(tw + ((size_t)(nf * 8 + ks) * 64 + lane) * 8);
            acc[nf] = __builtin_amdgcn_mfma_f32_16x16x32_bf16(ah, bh, acc[nf], 0, 0, 0);
        }
    }

#pragma unroll
    for (int nf = 0; nf < 8; ++nf)
        *(ushort4*)&Ls[nf * 16 + lr][wid * 16 + lg * 4] = cvt4(acc[nf]);
    __syncthreads();

    {
        const int col = tid >> 1, half = tid & 1;
        const int ky = col & 63, cs = col >> 6;
        u16* dst = Tt + (size_t)bi * 32768 + (size_t)ky * 512 + cs * 256 + hc * 64 + half * 32;
        const u16* srcp = &Ls[col][half * 32];
#pragma unroll
        for (int q = 0; q < 4; ++q)
            *(bf16x8*)(dst + q * 8) = *(const bf16x8*)(srcp + q * 8);
    }
}

// ---------------------------------------------------------------------------
// FB: block = bi. [64 ky x 128 col(im,kx)], K=512(cs,h).  (r9/r12 exact)
// ---------------------------------------------------------------------------
__global__ __launch_bounds__(256, 4) void fb_kernel(const u16* __restrict__ Tt,
                                                    const u16* __restrict__ tw,
                                                    float2* __restrict__ Y) {
    const int bi = blockIdx.x;
    const int tid = threadIdx.x;
    const int lane = tid & 63, wid = tid >> 6;
    const int lr = lane & 15, lg = lane >> 4;

    f32x4 acc[8] = {};
    const u16* ar = Tt + (size_t)bi * 32768 + (size_t)(wid * 16 + lr) * 512 + lg * 8;

#pragma unroll 2
    for (int ks = 0; ks < 16; ++ks) {
        bf16x8 ah = *(const bf16x8*)(ar + ks * 32);
#pragma unroll
        for (int nf = 0; nf < 8; ++nf) {
            bf16x8 bh = *(const bf16x8*)(tw + ((size_t)FB_OFF + (size_t)(nf * 16 + ks) * 64 + lane) * 8);
            acc[nf] = __builtin_amdgcn_mfma_f32_16x16x32_bf16(ah, bh, acc[nf], 0, 0, 0);
        }
    }

    __shared__ float L[64][129];
#pragma unroll
    for (int nf = 0; nf < 8; ++nf) {
        int col = nf * 16 + lr;
        int row = wid * 16 + lg * 4;
#pragma unroll
        for (int r = 0; r < 4; ++r) L[row + r][col] = acc[nf][r];
    }
    __syncthreads();
#pragma unroll
    for (int s = 0; s < 16; ++s) {
        int n = tid + s * 256;          // n = kx*64 + ky
        int ky = n & 63, kx = n >> 6;
        Y[(size_t)bi * 4096 + n] = make_float2(L[ky][kx], L[ky][64 + kx]);
    }
}

// ---------------------------------------------------------------------------
// MIX: in-place Y -> M, 8 modes/block (r13 structure). Grid = 512:
// kx = bid&63, kyo = bid>>6 (XCD co-location: bid%8 = kx%8 for siblings).
// i-loop unroll 4: 4x32B W in flight per thread (VGPR ~119 << cap 256).
// ---------------------------------------------------------------------------
__global__ __launch_bounds__(256) void mix_kernel(const float2* Yin,
                                                  const float* __restrict__ Wg,
                                                  float2* Mx) {
    const int kx    = blockIdx.x & 63;
    const int kyo   = blockIdx.x >> 6;
    const int tid   = threadIdx.x;
    const int kxky0 = kx * 64 + kyo * 8;

    __shared__ float2 Ys[128 * 64];

#pragma unroll
    for (int s = 0; s < 32; ++s) {
        int n = tid + s * 256;
        int b = n >> 10, i = (n >> 3) & 127, j = n & 7;
        Ys[i * 64 + b * 8 + j] = Yin[(size_t)(b * 128 + i) * 4096 + kxky0 + j];
    }
    __syncthreads();

    const int o  = tid >> 1;
    const int jh = tid & 1;

    float accre[8][4] = {{0.f}}, accim[8][4] = {{0.f}};
    const float* wp = Wg + ((size_t)o * 4096 + kxky0 + jh * 4) * 2;
    const size_t istride = (size_t)128 * 4096 * 2;

#pragma unroll 4
    for (int i = 0; i < 128; ++i) {
        float4 wa = *(const float4*)(wp + (size_t)i * istride);
        float4 wb = *(const float4*)(wp + (size_t)i * istride + 4);
#pragma unroll
        for (int b = 0; b < 8; ++b) {
            float4 y01 = *(const float4*)&Ys[i * 64 + b * 8 + jh * 4];
            float4 y23 = *(const float4*)&Ys[i * 64 + b * 8 + jh * 4 + 2];
            accre[b][0] = fmaf(y01.x, wa.x, fmaf(-y01.y, wa.y, accre[b][0]));
            accim[b][0] = fmaf(y01.x, wa.y, fmaf( y01.y, wa.x, accim[b][0]));
            accre[b][1] = fmaf(y01.z, wa.z, fmaf(-y01.w, wa.w, accre[b][1]));
            accim[b][1] = fmaf(y01.z, wa.w, fmaf( y01.w, wa.z, accim[b][1]));
            accre[b][2] = fmaf(y23.x, wb.x, fmaf(-y23.y, wb.y, accre[b][2]));
            accim[b][2] = fmaf(y23.x, wb.y, fmaf( y23.y, wb.x, accim[b][2]));
            accre[b][3] = fmaf(y23.z, wb.z, fmaf(-y23.w, wb.w, accre[b][3]));
            accim[b][3] = fmaf(y23.z, wb.w, fmaf( y23.w, wb.z, accim[b][3]));
        }
    }
#pragma unroll
    for (int b = 0; b < 8; ++b) {
        float2* mo = Mx + (size_t)(b * 128 + o) * 4096 + kxky0 + jh * 4;
        *(float4*)(mo)     = make_float4(accre[b][0], accim[b][0], accre[b][1], accim[b][1]);
        *(float4*)(mo + 2) = make_float4(accre[b][2], accim[b][2], accre[b][3], accim[b][3]);
    }
}

// ---------------------------------------------------------------------------
// INV (fused IB+IA): block = (bo, h-quarter hq). (r13 exact)
//   stage M -> LDS Ah[ky][k] (RNE bf16)                       [1 barrier]
//   IB: [64 ky x 128 (reim, hloc)] K=128 -> D-frags -> LDS Gh [1 barrier]
//   IA: [256 w x 64 hloc] K=128, A=twIA, B=Gh -> out          [1 barrier]
// ---------------------------------------------------------------------------
__global__ __launch_bounds__(256, 4) void inv_kernel(const float2* __restrict__ M,
                                                     const u16* __restrict__ tw,
                                                     float* __restrict__ out) {
    const int bo = blockIdx.x >> 2, hq = blockIdx.x & 3;
    const int tid = threadIdx.x;
    const int lane = tid & 63, wid = tid >> 6;
    const int lr = lane & 15, lg = lane >> 4;

    __shared__ u16 Ah[64][136];     // 17408 B
    __shared__ u16 Gh[64][136];     // 17408 B

    const float2* Mb = M + (size_t)bo * 4096;
#pragma unroll
    for (int s = 0; s < 16; ++s) {
        int n = tid + s * 256;
        float2 v = Mb[n];
        int kx = n >> 6, ky = n & 63;
        Ah[ky][kx]      = f2bf(v.x);
        Ah[ky][64 + kx] = f2bf(v.y);
    }
    __syncthreads();

    // ---- IB ----
    {
        const int reim = wid >> 1, csub = wid & 1;
        f32x4 bacc[4][2] = {};
#pragma unroll
        for (int ks = 0; ks < 4; ++ks) {
            bf16x8 bh[2];
#pragma unroll
            for (int nf = 0; nf < 2; ++nf) {
                int nf_g = reim * 16 + hq * 4 + csub * 2 + nf;
                bh[nf] = *(const bf16x8*)(tw + ((size_t)IB_OFF + (size_t)(nf_g * 4 + ks) * 64 + lane) * 8);
            }
#pragma unroll
            for (int mf = 0; mf < 4; ++mf) {
                bf16x8 ah = *(const bf16x8*)&Ah[mf * 16 + lr][ks * 32 + lg * 8];
#pragma unroll
                for (int nf = 0; nf < 2; ++nf)
                    bacc[mf][nf] = __builtin_amdgcn_mfma_f32_16x16x32_bf16(ah, bh[nf], bacc[mf][nf], 0, 0, 0);
            }
        }
        __syncthreads();
#pragma unroll
        for (int mf = 0; mf < 4; ++mf)
#pragma unroll
            for (int nf = 0; nf < 2; ++nf) {
                int hloc = csub * 32 + nf * 16 + lr;
                int kk   = reim * 64 + mf * 16 + lg * 4;
                *(ushort4*)&Gh[hloc][kk] = cvt4(bacc[mf][nf]);
            }
    }
    __syncthreads();

    // ---- IA ----
    {
        f32x4 cacc[4][4] = {};
#pragma unroll
        for (int ks = 0; ks < 4; ++ks) {
            bf16x8 ah[4];
#pragma unroll
            for (int mf = 0; mf < 4; ++mf) {
                int mf_g = wid * 4 + mf;
                ah[mf] = *(const bf16x8*)(tw + ((size_t)IA_OFF + (size_t)(mf_g * 4 + ks) * 64 + lane) * 8);
            }
#pragma unroll
            for (int nf = 0; nf < 4; ++nf) {
                bf16x8 bh = *(const bf16x8*)&Gh[nf * 16 + lr][ks * 32 + lg * 8];
#pragma unroll
                for (int mf = 0; mf < 4; ++mf)
                    cacc[mf][nf] = __builtin_amdgcn_mfma_f32_16x16x32_bf16(ah[mf], bh, cacc[mf][nf], 0, 0, 0);
            }
        }
#pragma unroll
        for (int mf = 0; mf < 4; ++mf)
#pragma unroll
            for (int nf = 0; nf < 4; ++nf) {
                int w0 = wid * 64 + mf * 16 + lg * 4;
                int h  = hq * 64 + nf * 16 + lr;
                *(f32x4*)(out + (size_t)bo * 65536 + (size_t)h * 256 + w0) = cacc[mf][nf];
            }
    }
}

// ---------------------------------------------------------------------------
extern "C" void kernel_launch(void* const* d_in, const int* in_sizes, int n_in,
                              void* d_out, int out_size, void* d_ws, size_t ws_size,
                              hipStream_t stream) {
    (void)in_sizes; (void)n_in; (void)out_size; (void)ws_size;
    const float* x  = (const float*)d_in[0];
    const float* wg = (const float*)d_in[1];
    float* outp = (float*)d_out;

    u16*    tw = (u16*)d_ws;                                          // 384 KB
    float2* Y  = (float2*)((char*)d_ws + 1048576);                    // 33.5 MB
    u16*    Tt = (u16*)((char*)d_ws + 1048576 + 33554432);            // 67 MB

    gen_kernel<<<96, 256, 0, stream>>>(tw);
    fa_kernel<<<4096, 256, 0, stream>>>(x, tw, Tt);
    fb_kernel<<<1024, 256, 0, stream>>>(Tt, tw, Y);
    mix_kernel<<<512, 256, 0, stream>>>(Y, wg, Y);
    inv_kernel<<<4096, 256, 0, stream>>>(Y, tw, outp);
}

// Round 16
// 371.255 us; speedup vs baseline: 1.3510x; 1.1356x over previous
//
#include <hip/hip_runtime.h>
#include <cstddef>

// FNO spectral conv via single-product bf16 MFMA (manual RNE) — FINAL (r13):
//   gen : twiddle tables in MFMA fragment order (384 KB, L2-hot)
//   FA  : x -> T_t bf16   (DFT along w)   4096 blocks, occ 4, MLP-16 loads
//   FB  : T_t -> Y float2 (DFT along h)   1024 blocks, occ 4
//   mix : per-mode complex channel GEMM, 8 modes/block, 512 blocks, 64KB LDS,
//         XCD co-location (bid = kyo*64+kx), unroll 2  — AT ITS W-BW FLOOR
//   INV : fused IB+IA per (bo, h-quarter), 3 barriers, 4 blocks/CU
// Ledger: r10 nt BAD (+247: breaks 128B line reuse); r11 occ5+unroll4 BAD
// (VGPR cap); r12 fa-MLP good (-6); r13 fused-inv good (-53, best 371.7);
// r14 4-mode mix BAD (+130: duplicate W loads = 2x W traffic); r15 mix
// unroll-4 BAD (+50: sibling-timing drift breaks L2 64B/64B line dedup).
// mix depends on kyo-sibling lockstep for W-line sharing — DO NOT PERTURB.
// absmax pinned at 7.629395e-06 (bit-identical arithmetic across rounds).

typedef __attribute__((ext_vector_type(8))) short bf16x8;
typedef __attribute__((ext_vector_type(4))) float f32x4;
typedef unsigned short u16;

static constexpr float T256 = 6.28318530717958647692f / 256.0f;
// f-slot bases (each slot = 64 lanes x 8 u16 = 16 B/lane)
static constexpr int FB_OFF = 4096, IB_OFF = 12288, IA_OFF = 20480;

// 3-op RNE bf16 (no NaN path — inputs finite by construction)
__device__ __forceinline__ u16 f2bf(float f) {
    unsigned u = __float_as_uint(f);
    return (u16)((u + 0x7FFFu + ((u >> 16) & 1u)) >> 16);
}
__device__ __forceinline__ ushort4 cvt4(const f32x4& a) {
    ushort4 o;
    o.x = f2bf(a[0]); o.y = f2bf(a[1]); o.z = f2bf(a[2]); o.w = f2bf(a[3]);
    return o;
}

// ---------------------------------------------------------------------------
// twiddle gen (proven layout)
// ---------------------------------------------------------------------------
__global__ __launch_bounds__(256) void gen_kernel(u16* __restrict__ tw) {
    const int t = blockIdx.x * 256 + threadIdx.x;       // 0..24575
    const int lane = t & 63, f = t >> 6;
    const int lr = lane & 15, lg = lane >> 4;
    bf16x8 hi;
#pragma unroll
    for (int j = 0; j < 8; ++j) {
        float v = 0.0f;
        if (f < 64) {                                   // FA  B[w][col]
            int nf = f >> 3, ks = f & 7;
            int col = nf * 16 + lr, k = ks * 32 + lg * 8 + j;
            int cc = (col < 64) ? col : (col - 64);
            float ss, sc; sincosf(T256 * (float)((k * cc) & 255), &ss, &sc);
            v = (col < 64) ? sc : ss;
        } else if (f < 192) {                           // FB  B[k][col]
            int fid = f - 64, nf = fid >> 4, ks = fid & 15;
            int col = nf * 16 + lr, k = ks * 32 + lg * 8 + j;
            int kx = col & 63, im = col >> 6;
            int h = k & 255, part = k >> 8;
            float ss, sc; sincosf(T256 * (float)((h * kx) & 255), &ss, &sc);
            if (im == 0) v = part ? -ss : sc;
            else         v = part ? -sc : -ss;
        } else if (f < 320) {                           // IB  B[k][col]
            int fid = f - 192, nf = fid >> 2, ks = fid & 3;
            int col = nf * 16 + lr, k = ks * 32 + lg * 8 + j;
            int h = col & 255, reim = col >> 8;
            int kx = k & 63, part = k >> 6;
            float ss, sc; sincosf(T256 * (float)((h * kx) & 255), &ss, &sc);
            if (reim == 0) v = part ? -ss : sc;
            else           v = part ?  sc :  ss;
        } else {                                        // IA  A[w][k]
            int fid = f - 320, mf = fid >> 2, ks = fid & 3;
            int w = mf * 16 + lr, k = ks * 32 + lg * 8 + j;
            int ky = k & 63, part = k >> 6;
            float wt = (ky ? 2.0f : 1.0f) * (1.0f / 65536.0f);
            float ss, sc; sincosf(T256 * (float)((w * ky) & 255), &ss, &sc);
            v = part ? (-wt * ss) : (wt * sc);
        }
        hi[j] = (short)f2bf(v);
    }
    *(bf16x8*)(tw + (size_t)t * 8) = hi;
}

// ---------------------------------------------------------------------------
// FA: block = (bi, h-chunk of 64). [64 h x 128 col(cs,ky)], K=256(w).
// All 16 x-loads issued up front (MLP); VGPR ~119 < occ-4 cap 128.
// ---------------------------------------------------------------------------
__global__ __launch_bounds__(256, 4) void fa_kernel(const float* __restrict__ x,
                                                    const u16* __restrict__ tw,
                                                    u16* __restrict__ Tt) {
    const int bi = blockIdx.x >> 2, hc = blockIdx.x & 3;
    const int tid = threadIdx.x;
    const int lane = tid & 63, wid = tid >> 6;
    const int lr = lane & 15, lg = lane >> 4;

    __shared__ u16 Ls[128][72];     // 18432 B

    f32x4 acc[8] = {};
    const float* xr = x + (size_t)bi * 65536 + (size_t)(hc * 64 + wid * 16 + lr) * 256 + lg * 8;

    f32x4 xv[16];
#pragma unroll
    for (int ks = 0; ks < 8; ++ks) {
        xv[2 * ks]     = *(const f32x4*)(xr + ks * 32);
        xv[2 * ks + 1] = *(const f32x4*)(xr + ks * 32 + 4);
    }

#pragma unroll
    for (int ks = 0; ks < 8; ++ks) {
        bf16x8 ah;
#pragma unroll
        for (int j = 0; j < 4; ++j) {
            ah[j]     = (short)f2bf(xv[2 * ks][j]);
            ah[4 + j] = (short)f2bf(xv[2 * ks + 1][j]);
        }
#pragma unroll
        for (int nf = 0; nf < 8; ++nf) {
            bf16x8 bh = *(const bf16x8*)(tw + ((size_t)(nf * 8 + ks) * 64 + lane) * 8);
            acc[nf] = __builtin_amdgcn_mfma_f32_16x16x32_bf16(ah, bh, acc[nf], 0, 0, 0);
        }
    }

#pragma unroll
    for (int nf = 0; nf < 8; ++nf)
        *(ushort4*)&Ls[nf * 16 + lr][wid * 16 + lg * 4] = cvt4(acc[nf]);
    __syncthreads();

    {
        const int col = tid >> 1, half = tid & 1;
        const int ky = col & 63, cs = col >> 6;
        u16* dst = Tt + (size_t)bi * 32768 + (size_t)ky * 512 + cs * 256 + hc * 64 + half * 32;
        const u16* srcp = &Ls[col][half * 32];
#pragma unroll
        for (int q = 0; q < 4; ++q)
            *(bf16x8*)(dst + q * 8) = *(const bf16x8*)(srcp + q * 8);
    }
}

// ---------------------------------------------------------------------------
// FB: block = bi. [64 ky x 128 col(im,kx)], K=512(cs,h).
// ---------------------------------------------------------------------------
__global__ __launch_bounds__(256, 4) void fb_kernel(const u16* __restrict__ Tt,
                                                    const u16* __restrict__ tw,
                                                    float2* __restrict__ Y) {
    const int bi = blockIdx.x;
    const int tid = threadIdx.x;
    const int lane = tid & 63, wid = tid >> 6;
    const int lr = lane & 15, lg = lane >> 4;

    f32x4 acc[8] = {};
    const u16* ar = Tt + (size_t)bi * 32768 + (size_t)(wid * 16 + lr) * 512 + lg * 8;

#pragma unroll 2
    for (int ks = 0; ks < 16; ++ks) {
        bf16x8 ah = *(const bf16x8*)(ar + ks * 32);
#pragma unroll
        for (int nf = 0; nf < 8; ++nf) {
            bf16x8 bh = *(const bf16x8*)(tw + ((size_t)FB_OFF + (size_t)(nf * 16 + ks) * 64 + lane) * 8);
            acc[nf] = __builtin_amdgcn_mfma_f32_16x16x32_bf16(ah, bh, acc[nf], 0, 0, 0);
        }
    }

    __shared__ float L[64][129];
#pragma unroll
    for (int nf = 0; nf < 8; ++nf) {
        int col = nf * 16 + lr;
        int row = wid * 16 + lg * 4;
#pragma unroll
        for (int r = 0; r < 4; ++r) L[row + r][col] = acc[nf][r];
    }
    __syncthreads();
#pragma unroll
    for (int s = 0; s < 16; ++s) {
        int n = tid + s * 256;          // n = kx*64 + ky
        int ky = n & 63, kx = n >> 6;
        Y[(size_t)bi * 4096 + n] = make_float2(L[ky][kx], L[ky][64 + kx]);
    }
}

// ---------------------------------------------------------------------------
// MIX: in-place Y -> M, 8 modes/block. Grid = 512: kx = bid&63, kyo = bid>>6
// (XCD co-location: bid%8 = kx%8 for all kyo-siblings -> shared W lines hit
// the same XCD's L2). Unroll 2. AT ITS W-BW FLOOR — do not restructure.
// ---------------------------------------------------------------------------
__global__ __launch_bounds__(256) void mix_kernel(const float2* Yin,
                                                  const float* __restrict__ Wg,
                                                  float2* Mx) {
    const int kx    = blockIdx.x & 63;
    const int kyo   = blockIdx.x >> 6;
    const int tid   = threadIdx.x;
    const int kxky0 = kx * 64 + kyo * 8;

    __shared__ float2 Ys[128 * 64];

#pragma unroll
    for (int s = 0; s < 32; ++s) {
        int n = tid + s * 256;
        int b = n >> 10, i = (n >> 3) & 127, j = n & 7;
        Ys[i * 64 + b * 8 + j] = Yin[(size_t)(b * 128 + i) * 4096 + kxky0 + j];
    }
    __syncthreads();

    const int o  = tid >> 1;
    const int jh = tid & 1;

    float accre[8][4] = {{0.f}}, accim[8][4] = {{0.f}};
    const float* wp = Wg + ((size_t)o * 4096 + kxky0 + jh * 4) * 2;
    const size_t istride = (size_t)128 * 4096 * 2;

#pragma unroll 2
    for (int i = 0; i < 128; ++i) {
        float4 wa = *(const float4*)(wp + (size_t)i * istride);
        float4 wb = *(const float4*)(wp + (size_t)i * istride + 4);
#pragma unroll
        for (int b = 0; b < 8; ++b) {
            float4 y01 = *(const float4*)&Ys[i * 64 + b * 8 + jh * 4];
            float4 y23 = *(const float4*)&Ys[i * 64 + b * 8 + jh * 4 + 2];
            accre[b][0] = fmaf(y01.x, wa.x, fmaf(-y01.y, wa.y, accre[b][0]));
            accim[b][0] = fmaf(y01.x, wa.y, fmaf( y01.y, wa.x, accim[b][0]));
            accre[b][1] = fmaf(y01.z, wa.z, fmaf(-y01.w, wa.w, accre[b][1]));
            accim[b][1] = fmaf(y01.z, wa.w, fmaf( y01.w, wa.z, accim[b][1]));
            accre[b][2] = fmaf(y23.x, wb.x, fmaf(-y23.y, wb.y, accre[b][2]));
            accim[b][2] = fmaf(y23.x, wb.y, fmaf( y23.y, wb.x, accim[b][2]));
            accre[b][3] = fmaf(y23.z, wb.z, fmaf(-y23.w, wb.w, accre[b][3]));
            accim[b][3] = fmaf(y23.z, wb.w, fmaf( y23.w, wb.z, accim[b][3]));
        }
    }
#pragma unroll
    for (int b = 0; b < 8; ++b) {
        float2* mo = Mx + (size_t)(b * 128 + o) * 4096 + kxky0 + jh * 4;
        *(float4*)(mo)     = make_float4(accre[b][0], accim[b][0], accre[b][1], accim[b][1]);
        *(float4*)(mo + 2) = make_float4(accre[b][2], accim[b][2], accre[b][3], accim[b][3]);
    }
}

// ---------------------------------------------------------------------------
// INV (fused IB+IA): block = (bo, h-quarter hq).
//   stage M -> LDS Ah[ky][k] (RNE bf16)                       [1 barrier]
//   IB: [64 ky x 128 (reim, hloc)] K=128 -> D-frags -> LDS Gh [1 barrier]
//   IA: [256 w x 64 hloc] K=128, A=twIA, B=Gh -> out          [1 barrier]
// LDS 34816 B -> 4 blocks/CU.
// ---------------------------------------------------------------------------
__global__ __launch_bounds__(256, 4) void inv_kernel(const float2* __restrict__ M,
                                                     const u16* __restrict__ tw,
                                                     float* __restrict__ out) {
    const int bo = blockIdx.x >> 2, hq = blockIdx.x & 3;
    const int tid = threadIdx.x;
    const int lane = tid & 63, wid = tid >> 6;
    const int lr = lane & 15, lg = lane >> 4;

    __shared__ u16 Ah[64][136];     // 17408 B
    __shared__ u16 Gh[64][136];     // 17408 B

    const float2* Mb = M + (size_t)bo * 4096;
#pragma unroll
    for (int s = 0; s < 16; ++s) {
        int n = tid + s * 256;
        float2 v = Mb[n];
        int kx = n >> 6, ky = n & 63;
        Ah[ky][kx]      = f2bf(v.x);
        Ah[ky][64 + kx] = f2bf(v.y);
    }
    __syncthreads();

    // ---- IB ----
    {
        const int reim = wid >> 1, csub = wid & 1;
        f32x4 bacc[4][2] = {};
#pragma unroll
        for (int ks = 0; ks < 4; ++ks) {
            bf16x8 bh[2];
#pragma unroll
            for (int nf = 0; nf < 2; ++nf) {
                int nf_g = reim * 16 + hq * 4 + csub * 2 + nf;
                bh[nf] = *(const bf16x8*)(tw + ((size_t)IB_OFF + (size_t)(nf_g * 4 + ks) * 64 + lane) * 8);
            }
#pragma unroll
            for (int mf = 0; mf < 4; ++mf) {
                bf16x8 ah = *(const bf16x8*)&Ah[mf * 16 + lr][ks * 32 + lg * 8];
#pragma unroll
                for (int nf = 0; nf < 2; ++nf)
                    bacc[mf][nf] = __builtin_amdgcn_mfma_f32_16x16x32_bf16(ah, bh[nf], bacc[mf][nf], 0, 0, 0);
            }
        }
        __syncthreads();
#pragma unroll
        for (int mf = 0; mf < 4; ++mf)
#pragma unroll
            for (int nf = 0; nf < 2; ++nf) {
                int hloc = csub * 32 + nf * 16 + lr;
                int kk   = reim * 64 + mf * 16 + lg * 4;
                *(ushort4*)&Gh[hloc][kk] = cvt4(bacc[mf][nf]);
            }
    }
    __syncthreads();

    // ---- IA ----
    {
        f32x4 cacc[4][4] = {};
#pragma unroll
        for (int ks = 0; ks < 4; ++ks) {
            bf16x8 ah[4];
#pragma unroll
            for (int mf = 0; mf < 4; ++mf) {
                int mf_g = wid * 4 + mf;
                ah[mf] = *(const bf16x8*)(tw + ((size_t)IA_OFF + (size_t)(mf_g * 4 + ks) * 64 + lane) * 8);
            }
#pragma unroll
            for (int nf = 0; nf < 4; ++nf) {
                bf16x8 bh = *(const bf16x8*)&Gh[nf * 16 + lr][ks * 32 + lg * 8];
#pragma unroll
                for (int mf = 0; mf < 4; ++mf)
                    cacc[mf][nf] = __builtin_amdgcn_mfma_f32_16x16x32_bf16(ah[mf], bh, cacc[mf][nf], 0, 0, 0);
            }
        }
#pragma unroll
        for (int mf = 0; mf < 4; ++mf)
#pragma unroll
            for (int nf = 0; nf < 4; ++nf) {
                int w0 = wid * 64 + mf * 16 + lg * 4;
                int h  = hq * 64 + nf * 16 + lr;
                *(f32x4*)(out + (size_t)bo * 65536 + (size_t)h * 256 + w0) = cacc[mf][nf];
            }
    }
}

// ---------------------------------------------------------------------------
extern "C" void kernel_launch(void* const* d_in, const int* in_sizes, int n_in,
                              void* d_out, int out_size, void* d_ws, size_t ws_size,
                              hipStream_t stream) {
    (void)in_sizes; (void)n_in; (void)out_size; (void)ws_size;
    const float* x  = (const float*)d_in[0];
    const float* wg = (const float*)d_in[1];
    float* outp = (float*)d_out;

    u16*    tw = (u16*)d_ws;                                          // 384 KB
    float2* Y  = (float2*)((char*)d_ws + 1048576);                    // 33.5 MB
    u16*    Tt = (u16*)((char*)d_ws + 1048576 + 33554432);            // 67 MB

    gen_kernel<<<96, 256, 0, stream>>>(tw);
    fa_kernel<<<4096, 256, 0, stream>>>(x, tw, Tt);
    fb_kernel<<<1024, 256, 0, stream>>>(Tt, tw, Y);
    mix_kernel<<<512, 256, 0, stream>>>(Y, wg, Y);
    inv_kernel<<<4096, 256, 0, stream>>>(Y, tw, outp);
}